// Round 4
// baseline (409.205 us; speedup 1.0000x reference)
//
#include <hip/hip_runtime.h>

// VectorQuantizer on MI355X — round 4: same numpy-exact scoring arithmetic as
// round 3 (PASSED), restructured for FMA throughput:
//   - 4m x 8k register micro-tile (32 FMA per 3 ds_read_b128)
//   - chunk-staged z and e in LDS (26 KB/block -> 3 blocks/CU vs 2)
//   - ||z||^2 (numpy pairwise order) precomputed in a separate kernel
// x: (32,256,32,32) fp32, codebook: (1024,256) fp32.
// Outputs concat: quantized (8388608 f32), vq_loss (1 f32), indices (32768 as f32).

#define NUM_K 1024
#define DIM   256
#define HW    1024          // H*W
#define N_TOT 32768         // B*H*W
#define TM    64            // m-tile per block
#define TK    128           // k-tile
#define DB    32            // d-chunk (numpy fold chunk — do not change)
#define LOSS_OFF 8388608
#define IDX_OFF  8388609

// numpy pairwise sum of squares over 256 elements, exact numpy order:
// two 128-blocks, each with 8 accumulators r[j] += fl(v*v), combined
// ((r0+r1)+(r2+r3))+((r4+r5)+(r6+r7)), then block0+block1.
__device__ __forceinline__ float np_sumsq_256(const float* p, int stride) {
    float s[2];
    #pragma unroll
    for (int h = 0; h < 2; ++h) {
        const float* base = p + (size_t)h * 128 * stride;
        float r[8];
        #pragma unroll
        for (int j = 0; j < 8; ++j) {
            float v = base[(size_t)j * stride];
            r[j] = __fmul_rn(v, v);
        }
        for (int i = 8; i < 128; i += 8) {
            #pragma unroll
            for (int j = 0; j < 8; ++j) {
                float v = base[(size_t)(i + j) * stride];
                r[j] = __fadd_rn(r[j], __fmul_rn(v, v));
            }
        }
        s[h] = __fadd_rn(__fadd_rn(__fadd_rn(r[0], r[1]), __fadd_rn(r[2], r[3])),
                         __fadd_rn(__fadd_rn(r[4], r[5]), __fadd_rn(r[6], r[7])));
    }
    return __fadd_rn(s[0], s[1]);
}

__global__ __launch_bounds__(256) void u2_kernel(const float* __restrict__ cb,
                                                 float* __restrict__ u2) {
    int k = blockIdx.x * 256 + threadIdx.x;     // 4 blocks x 256
    u2[k] = np_sumsq_256(cb + (size_t)k * DIM, 1);
}

__global__ __launch_bounds__(256) void t2_kernel(const float* __restrict__ x,
                                                 float* __restrict__ t2) {
    int n = blockIdx.x * 256 + threadIdx.x;     // 128 blocks x 256
    int b = n >> 10;
    int r = n & (HW - 1);
    t2[n] = np_sumsq_256(x + (size_t)b * (DIM * HW) + r, HW);
}

__global__ __launch_bounds__(256, 3) void vq_main(const float* __restrict__ x,
                                                  const float* __restrict__ cb,
                                                  const float* __restrict__ u2,
                                                  const float* __restrict__ t2,
                                                  float* __restrict__ out) {
    __shared__ float zC[DB][TM];       // 8 KB   zC[d][m], d within chunk
    __shared__ float eC[DB][TK];       // 16 KB  eC[d][k]
    __shared__ float red_v[4][TM];     // 1 KB
    __shared__ int   red_k[4][TM];     // 1 KB
    __shared__ int   bestk_s[TM];      // 256 B
    __shared__ float wsum[4];

    const int t  = threadIdx.x;
    const int g  = blockIdx.x;          // 512 blocks
    const int n0 = g * TM;
    const int b  = n0 >> 10;            // /1024
    const int r0 = n0 & (HW - 1);
    const size_t xbase = (size_t)b * (DIM * HW) + r0;

    const int tm4 = (t & 15) * 4;       // 4 m's per thread
    const int tk8 = (t >> 4) * 8;       // 8 k's (within k-tile) per thread

    // numpy-order ||z||^2 for this thread's 4 rows
    float tsr[4];
    #pragma unroll
    for (int i = 0; i < 4; ++i) tsr[i] = t2[n0 + tm4 + i];

    float best_v[4] = {3.4e38f, 3.4e38f, 3.4e38f, 3.4e38f};
    int   best_k[4] = {0, 0, 0, 0};

    // staging index precompute
    const int zf4 = (t & 15) * 4;       // m offset for z staging
    const int zdr = t >> 4;             // d row for z staging
    const int ekk = t >> 1;             // k row for e staging (0..127)
    const int edh = (t & 1) * 16;       // d half for e staging

    for (int kt = 0; kt < NUM_K / TK; ++kt) {
        const int k0 = kt * TK;
        double accd[4][8];
        #pragma unroll
        for (int i = 0; i < 4; ++i)
            #pragma unroll
            for (int j = 0; j < 8; ++j) accd[i][j] = 0.0;

        for (int dc = 0; dc < DIM / DB; ++dc) {
            const int d0 = dc * DB;
            // stage zC[d][m] = x[xbase + (d0+d)*HW + m]  (coalesced float4)
            #pragma unroll
            for (int it = 0; it < 2; ++it) {
                int d = it * 16 + zdr;
                float4 v = *(const float4*)(x + xbase + (size_t)(d0 + d) * HW + zf4);
                *(float4*)&zC[d][zf4] = v;
            }
            // stage eC[d][k] = cb[(k0+k)*DIM + d0+d]  (16 floats per thread)
            {
                const float* src = cb + (size_t)(k0 + ekk) * DIM + d0 + edh;
                float4 a0 = *(const float4*)(src + 0);
                float4 a1 = *(const float4*)(src + 4);
                float4 a2 = *(const float4*)(src + 8);
                float4 a3 = *(const float4*)(src + 12);
                eC[edh + 0][ekk] = a0.x;  eC[edh + 1][ekk] = a0.y;
                eC[edh + 2][ekk] = a0.z;  eC[edh + 3][ekk] = a0.w;
                eC[edh + 4][ekk] = a1.x;  eC[edh + 5][ekk] = a1.y;
                eC[edh + 6][ekk] = a1.z;  eC[edh + 7][ekk] = a1.w;
                eC[edh + 8][ekk] = a2.x;  eC[edh + 9][ekk] = a2.y;
                eC[edh + 10][ekk] = a2.z; eC[edh + 11][ekk] = a2.w;
                eC[edh + 12][ekk] = a3.x; eC[edh + 13][ekk] = a3.y;
                eC[edh + 14][ekk] = a3.z; eC[edh + 15][ekk] = a3.w;
            }
            __syncthreads();

            // fp32 chunk accumulators (reset per 32-d chunk; numpy-chunk order)
            float af[4][8];
            #pragma unroll
            for (int i = 0; i < 4; ++i)
                #pragma unroll
                for (int j = 0; j < 8; ++j) af[i][j] = 0.f;

            #pragma unroll 4
            for (int d = 0; d < DB; ++d) {
                float4 zv  = *(const float4*)&zC[d][tm4];
                float4 ev0 = *(const float4*)&eC[d][tk8];
                float4 ev1 = *(const float4*)&eC[d][tk8 + 4];
                float za[4] = {zv.x, zv.y, zv.z, zv.w};
                float ea[8] = {ev0.x, ev0.y, ev0.z, ev0.w,
                               ev1.x, ev1.y, ev1.z, ev1.w};
                #pragma unroll
                for (int i = 0; i < 4; ++i)
                    #pragma unroll
                    for (int j = 0; j < 8; ++j)
                        af[i][j] = fmaf(za[i], ea[j], af[i][j]);
            }
            // fold chunk into fp64 (same order/boundaries as round 3)
            #pragma unroll
            for (int i = 0; i < 4; ++i)
                #pragma unroll
                for (int j = 0; j < 8; ++j) accd[i][j] += (double)af[i][j];
            __syncthreads();
        }

        // ---- replicate numpy: d = fl32( fl32(T_n + U_k) - 2*fl32(dot) ) ----
        float4 uv0 = *(const float4*)(u2 + k0 + tk8);
        float4 uv1 = *(const float4*)(u2 + k0 + tk8 + 4);
        float ua[8] = {uv0.x, uv0.y, uv0.z, uv0.w, uv1.x, uv1.y, uv1.z, uv1.w};
        #pragma unroll
        for (int j = 0; j < 8; ++j) {
            const int kk = k0 + tk8 + j;
            #pragma unroll
            for (int i = 0; i < 4; ++i) {
                float m32 = (float)accd[i][j];              // fl32(dot)
                float c   = __fmul_rn(2.0f, m32);           // exact
                float t1  = __fadd_rn(tsr[i], ua[j]);       // fl32(T+U)
                float d32 = __fsub_rn(t1, c);               // fl32(t1-c)
                // strict < keeps the earliest k (ks ascend within a thread)
                if (d32 < best_v[i]) { best_v[i] = d32; best_k[i] = kk; }
            }
        }
    }

    // ---- argmin reduction across the 4 tk-subgroups within each wave ----
    #pragma unroll
    for (int i = 0; i < 4; ++i) {
        float v = best_v[i]; int k = best_k[i];
        #pragma unroll
        for (int off = 16; off < 64; off <<= 1) {
            float ov = __shfl_xor(v, off, 64);
            int   ok = __shfl_xor(k, off, 64);
            if (ov < v || (ov == v && ok < k)) { v = ov; k = ok; }
        }
        best_v[i] = v; best_k[i] = k;
    }
    const int wv = t >> 6;              // wave id 0..3
    if ((t & 63) < 16) {
        #pragma unroll
        for (int i = 0; i < 4; ++i) {
            red_v[wv][tm4 + i] = best_v[i];
            red_k[wv][tm4 + i] = best_k[i];
        }
    }
    __syncthreads();
    if (t < TM) {
        float bv = red_v[0][t]; int bk = red_k[0][t];
        #pragma unroll
        for (int q = 1; q < 4; ++q) {
            float v = red_v[q][t]; int k = red_k[q][t];
            if (v < bv || (v == bv && k < bk)) { bv = v; bk = k; }
        }
        bestk_s[t] = bk;
        out[IDX_OFF + n0 + t] = (float)bk;   // indices as float
    }
    __syncthreads();

    // ---- epilogue: quantized output + fused loss (x re-read from global) ----
    float lsum = 0.f;
    {
        const int m = t & 63;
        const int kq = bestk_s[m];
        const float* crow = cb + (size_t)kq * DIM;
        for (int c = (t >> 6); c < DIM; c += 4) {
            float qv = crow[c];
            float xv = x[xbase + (size_t)c * HW + m];
            float d  = qv - xv;
            lsum = fmaf(d, d, lsum);
            out[xbase + (size_t)c * HW + m] = qv;
        }
    }
    #pragma unroll
    for (int off = 32; off > 0; off >>= 1) lsum += __shfl_down(lsum, off, 64);
    if ((t & 63) == 0) wsum[wv] = lsum;
    __syncthreads();
    if (t == 0) {
        float s = (wsum[0] + wsum[1]) + (wsum[2] + wsum[3]);
        // vq_loss = q_latent + 0.25*e_latent, both equal mean((q-x)^2)
        atomicAdd(out + LOSS_OFF, s * (1.25f / 8388608.0f));
    }
}

extern "C" void kernel_launch(void* const* d_in, const int* in_sizes, int n_in,
                              void* d_out, int out_size, void* d_ws, size_t ws_size,
                              hipStream_t stream) {
    const float* x  = (const float*)d_in[0];
    const float* cb = (const float*)d_in[1];
    float* out = (float*)d_out;
    float* u2  = (float*)d_ws;                  // 4 KB
    float* t2  = (float*)d_ws + NUM_K;          // 128 KB

    // zero the loss slot (atomicAdd target); graph-capture-safe
    hipMemsetAsync(out + LOSS_OFF, 0, sizeof(float), stream);
    u2_kernel<<<NUM_K / 256, 256, 0, stream>>>(cb, u2);
    t2_kernel<<<N_TOT / 256, 256, 0, stream>>>(x, t2);
    vq_main<<<N_TOT / TM, 256, 0, stream>>>(x, cb, u2, t2, out);
}